// Round 9
// baseline (172.301 us; speedup 1.0000x reference)
//
#include <hip/hip_runtime.h>
#include <cfloat>

typedef __attribute__((ext_vector_type(8))) short bf16x8;
typedef __attribute__((ext_vector_type(4))) float f32x4;
typedef __attribute__((ext_vector_type(8))) unsigned short u16x8;

#define NROW 32768
#define ZQ_OFF   0
#define LOSS_OFF 8388608
#define PERP_OFF 8388609
#define IDX_OFF  8388610
#define DIST_OFF 8421378

// ws byte offsets
#define WSB_AHI  0x0
#define WSB_BHI  0x1000000
#define WSB_RN   0x2100000
#define WSB_EN   0x2120000
#define WSB_PKEY 0x2200000
#define WSB_CNT  0x2620000
#define WSB_LOSS 0x2621000   // = WSB_CNT + 4096 (contiguous after counts)
#define WSB_CTR  0x2621004   // zeroed together with counts+loss (1026 floats)

__device__ __forceinline__ float sq_rn(float x) { return __fmul_rn(x, x); }

__device__ __forceinline__ unsigned enc_f(float f) {
  unsigned u = __float_as_uint(f);
  return (u & 0x80000000u) ? ~u : (u | 0x80000000u);
}
__device__ __forceinline__ float dec_f(unsigned e) {
  unsigned u = (e & 0x80000000u) ? (e ^ 0x80000000u) : ~e;
  return __uint_as_float(u);
}

__device__ __forceinline__ unsigned short bf16_rne(float f) {
  unsigned u = __float_as_uint(f);
  unsigned r = u + 0x7fffu + ((u >> 16) & 1u);
  return (unsigned short)(r >> 16);
}

__device__ __forceinline__ void gload16(const void* g, void* l) {
  __builtin_amdgcn_global_load_lds(
      (const __attribute__((address_space(1))) unsigned int*)g,
      (__attribute__((address_space(3))) unsigned int*)l, 16, 0, 0);
}

// numpy pairwise_sum order for 256-length sum of squares (load-bearing).
__device__ float pairwise_norm256(const float* __restrict__ p, int stride) {
  float h[2];
#pragma unroll
  for (int half = 0; half < 2; ++half) {
    const float* q = p + (size_t)half * 128 * stride;
    float r[8];
#pragma unroll
    for (int j = 0; j < 8; ++j) r[j] = sq_rn(q[(size_t)j * stride]);
    for (int d8 = 8; d8 < 128; d8 += 8) {
#pragma unroll
      for (int j = 0; j < 8; ++j)
        r[j] = __fadd_rn(r[j], sq_rn(q[(size_t)(d8 + j) * stride]));
    }
    h[half] = __fadd_rn(__fadd_rn(__fadd_rn(r[0], r[1]), __fadd_rn(r[2], r[3])),
                        __fadd_rn(__fadd_rn(r[4], r[5]), __fadd_rn(r[6], r[7])));
  }
  return __fadd_rn(h[0], h[1]);
}

// One launch for all prep work:
//   blocks 0..511   : z_e -> A bf16 plane (64 rows each) + rownorm (numpy order)
//   blocks 512..639 : emb -> B bf16 plane (pre-swizzled)
//   blocks 640..643 : embnorm
//   block  644      : zero counts+loss+ctr
__launch_bounds__(256)
__global__ void prep_all_kernel(const float* __restrict__ z_e,
                                const float* __restrict__ emb,
                                unsigned short* __restrict__ ahi,
                                unsigned short* __restrict__ bhi,
                                float* __restrict__ rownorm,
                                float* __restrict__ embnorm,
                                float* __restrict__ zero_region) {
  __shared__ float xt[64][68];
  __shared__ float hs[64][2];
  const int t = threadIdx.x;
  if (blockIdx.x >= 512) {
    const int bx = blockIdx.x - 512;
    if (bx >= 132) {
      for (int i = t; i < 1026; i += 256) zero_region[i] = 0.f;
      return;
    }
    if (bx >= 128) {
      const int k = ((bx - 128) << 8) + t;
      embnorm[k] = pairwise_norm256(emb + ((size_t)k << 8), 1);
      return;
    }
    const int tg = (bx << 8) + t;   // 32768
    const int k = tg >> 5, cd = tg & 31;
    const float4 v0 = *(const float4*)(emb + ((size_t)k << 8) + cd * 8);
    const float4 v1 = *(const float4*)(emb + ((size_t)k << 8) + cd * 8 + 4);
    const float xs[8] = {v0.x, v0.y, v0.z, v0.w, v1.x, v1.y, v1.z, v1.w};
    u16x8 vh;
#pragma unroll
    for (int u = 0; u < 8; ++u) vh[u] = (short)bf16_rne(xs[u]);
    const size_t pos = (((size_t)(k >> 7)) << 12) + ((size_t)(cd >> 3) << 10)
                     + ((size_t)(k & 127) << 3) + (size_t)((cd & 7) ^ (k & 7));
    *(u16x8*)(bhi + pos * 8) = vh;
    return;
  }
  // ---- A-plane + rownorm: 64 rows per block ----
  const int bx = blockIdx.x;
  const int ntile = bx >> 1;
  const int shalf = bx & 1;
  const int n0 = bx << 6;                 // first global row of this block
  const int b = n0 >> 10, s0 = n0 & 1023;
  const size_t zb = ((size_t)b << 18) + (size_t)s0;
  const int mys = t & 63;                 // row within block
  const int myhalf = (t >> 6) & 1;        // d-half (valid for t<128)
  float r[8];
#pragma unroll
  for (int j = 0; j < 8; ++j) r[j] = 0.f;   // +0 + x*x bit-exact (squares >= 0)
  for (int dt = 0; dt < 4; ++dt) {
#pragma unroll
    for (int p = 0; p < 4; ++p) {
      const int idx = (p << 8) + t;        // 0..1023
      const int dd = idx >> 4;             // 0..63
      const int sq = (idx & 15) << 2;      // 0..60
      const float4 v = *(const float4*)(z_e + zb + ((size_t)((dt << 6) + dd) << 10) + sq);
      const int sw = ((dd >> 3) & 3) << 3;
      *(float4*)(&xt[dd][sq ^ sw]) = v;
    }
    __syncthreads();
    if (t < 128 && (dt >> 1) == myhalf) {
#pragma unroll
      for (int g = 0; g < 8; ++g) {
        const int col = mys ^ ((g & 3) << 3);
#pragma unroll
        for (int j = 0; j < 8; ++j)
          r[j] = __fadd_rn(r[j], sq_rn(xt[(g << 3) + j][col]));
      }
    }
#pragma unroll
    for (int p = 0; p < 2; ++p) {
      const int idx = (p << 8) + t;        // 0..511
      const int sl = idx >> 3, c = idx & 7;
      const int sw = (c & 3) << 3;
      u16x8 vh;
#pragma unroll
      for (int u = 0; u < 8; ++u)
        vh[u] = (short)bf16_rne(xt[(c << 3) + u][sl ^ sw]);
      const int sg = (shalf << 6) + sl;    // row within 128-row ntile
      const size_t pos = ((size_t)ntile << 12) + ((size_t)dt << 10)
                       + (size_t)(sg << 3) + (size_t)(c ^ (sg & 7));
      *(u16x8*)(ahi + pos * 8) = vh;
    }
    __syncthreads();
  }
  if (t < 128) {
    const float h = __fadd_rn(__fadd_rn(__fadd_rn(r[0], r[1]), __fadd_rn(r[2], r[3])),
                              __fadd_rn(__fadd_rn(r[4], r[5]), __fadd_rn(r[6], r[7])));
    hs[mys][myhalf] = h;
  }
  __syncthreads();
  if (t < 64) rownorm[n0 + t] = __fadd_rn(hs[t][0], hs[t][1]);
}

#define LDS_A 0
#define LDS_B 16384

// 128x128 tile, 4 waves of 64x64, single plain-bf16 MFMA per fragment pair
// (proposal eps <= ||x||*||e||*2^-8 ~ 1.2e-3; refine window 3e-3 covers).
// XCD-chunked block mapping for A-tile L2 reuse. dist stores are nontemporal
// (written once, re-read sparsely; keeps L2 for A/B tiles).
__launch_bounds__(256, 4)
__global__ void dist_kernel(const unsigned short* __restrict__ ahi,
                            const unsigned short* __restrict__ bhi,
                            const float* __restrict__ rownorm,
                            const float* __restrict__ embnorm,
                            float* __restrict__ dist,
                            unsigned long long* __restrict__ pkey) {
  __shared__ char lds[32768];
  const int tid = threadIdx.x;
  const int lane = tid & 63;
  const int wv = tid >> 6;
  const int wr = wv >> 1, wc = wv & 1;
  const int bid = blockIdx.x;
  const int xcd = bid & 7;
  const int jj = bid >> 3;
  const int ntile = (xcd << 5) + (jj >> 3);
  const int ktile = jj & 7;

  const unsigned short* gsrc = (wv < 2) ? ahi + ((size_t)ntile << 15)
                                        : bhi + ((size_t)ktile << 15);
  char* ldsBase = lds + ((wv >> 1) << 14);

  f32x4 acc[4][4];
#pragma unroll
  for (int i = 0; i < 4; ++i)
#pragma unroll
    for (int j = 0; j < 4; ++j) acc[i][j] = (f32x4){0.f, 0.f, 0.f, 0.f};

  for (int s = 0; s < 4; ++s) {
    {
      const unsigned short* g = gsrc + ((size_t)s << 13);
#pragma unroll
      for (int q = 0; q < 8; ++q) {
        const int cq = ((wv & 1) << 3) + q;
        gload16(g + ((size_t)(cq * 64 + lane) << 3), ldsBase + cq * 1024);
      }
    }
    __syncthreads();
#pragma unroll
    for (int half = 0; half < 2; ++half) {
      const int kb = half << 2;
      bf16x8 ah[4], bh[4];
#pragma unroll
      for (int i = 0; i < 4; ++i) {
        const int row = (wr << 6) + (i << 4) + (lane & 15);
        const int ch = (kb + (lane >> 4)) ^ (row & 7);
        ah[i] = *(const bf16x8*)(lds + LDS_A + ((row << 3) + ch) * 16);
      }
#pragma unroll
      for (int j = 0; j < 4; ++j) {
        const int row = (wc << 6) + (j << 4) + (lane & 15);
        const int ch = (kb + (lane >> 4)) ^ (row & 7);
        bh[j] = *(const bf16x8*)(lds + LDS_B + ((row << 3) + ch) * 16);
      }
#pragma unroll
      for (int i = 0; i < 4; ++i)
#pragma unroll
        for (int j = 0; j < 4; ++j)
          acc[i][j] = __builtin_amdgcn_mfma_f32_16x16x32_bf16(ah[i], bh[j], acc[i][j], 0, 0, 0);
    }
    __syncthreads();
  }
  const int n0 = (ntile << 7) + (wr << 6);
  const int k0 = (ktile << 7) + (wc << 6);
  const int g = lane >> 4, tl = lane & 15;
  const int tileidx = (ktile << 1) + wc;
  float en[4];
#pragma unroll
  for (int j = 0; j < 4; ++j) en[j] = embnorm[k0 + (j << 4) + tl];
#pragma unroll
  for (int i = 0; i < 4; ++i) {
#pragma unroll
    for (int r = 0; r < 4; ++r) {
      const int n = n0 + (i << 4) + (g << 2) + r;
      const float rn = rownorm[n];
      float* drow = dist + (size_t)n * 1024 + k0 + tl;
      unsigned long long key = ~0ULL;
#pragma unroll
      for (int j = 0; j < 4; ++j) {
        const float dv = __fsub_rn(__fadd_rn(rn, en[j]), __fmul_rn(2.0f, acc[i][j][r]));
        __builtin_nontemporal_store(dv, &drow[j << 4]);
        const unsigned long long c =
            ((unsigned long long)enc_f(dv) << 32) | (unsigned)(k0 + (j << 4) + tl);
        key = c < key ? c : key;
      }
#pragma unroll
      for (int mm = 1; mm < 16; mm <<= 1) {
        const unsigned long long o = __shfl_xor(key, mm, 64);
        key = o < key ? o : key;
      }
      if (tl == 0) pkey[(size_t)n * 16 + tileidx] = key;
    }
  }
}

// Fused refine + straight-through + loss + histogram + index output + final.
// Refine semantics unchanged (16-wide pkey, 3e-3 window, exact fp64-dot re-eval,
// (value,index) order). Final runs in the last-finishing block; ordering by
// s_waitcnt vmcnt(0) (NO threadfence / L2 flush — that was round 7's storm).
__launch_bounds__(256)
__global__ void rzq_kernel(const float* __restrict__ z_e,
                           const float* __restrict__ emb,
                           const float* __restrict__ rownorm,
                           const float* __restrict__ embnorm,
                           const float* __restrict__ dist,
                           const unsigned long long* __restrict__ pkey,
                           float* __restrict__ out,
                           float* __restrict__ counts,
                           float* __restrict__ lossacc,
                           unsigned* __restrict__ ctr) {
  __shared__ float xl[16][260];
  __shared__ int bk_s[16];
  __shared__ float wredf[4];
  __shared__ unsigned lastflag;
  const int t = threadIdx.x;
  const int s0 = blockIdx.x << 4;
  const int b = s0 >> 10, sb = s0 & 1023;
  {
    const int d = t >> 2;
    const int s4 = (t & 3) << 2;
#pragma unroll
    for (int p = 0; p < 4; ++p) {
      const int dd = d + p * 64;
      const float4 v = *(const float4*)(z_e + ((size_t)b << 18) + ((size_t)dd << 10) + sb + s4);
      xl[s4 + 0][dd] = v.x; xl[s4 + 1][dd] = v.y;
      xl[s4 + 2][dd] = v.z; xl[s4 + 3][dd] = v.w;
    }
  }
  __syncthreads();
  const int wv = t >> 6, lane = t & 63;
  for (int rr = 0; rr < 4; ++rr) {
    const int srow = (wv << 2) + rr;
    const int n = s0 + srow;
    const unsigned long long mypk = (lane < 16) ? pkey[(size_t)n * 16 + lane] : ~0ULL;
    unsigned long long key = mypk;
#pragma unroll
    for (int mm = 1; mm < 64; mm <<= 1) {
      const unsigned long long o = __shfl_xor(key, mm, 64);
      key = o < key ? o : key;
    }
    const float v1 = dec_f((unsigned)(key >> 32));
    const unsigned ue = (__float_as_uint(v1) >> 23) & 0xffu;
    const float ulp = __uint_as_float((ue - 23) << 23);
    const float w = v1 + 2.0f * ulp + 3e-3f;
    unsigned qmask = (unsigned)(__ballot(dec_f((unsigned)(mypk >> 32)) <= w) & 0xffffULL);
    const float rn = rownorm[n];
    const float4 xv = *(const float4*)(&xl[srow][lane << 2]);
    unsigned long long best = ~0ULL;
    while (qmask) {
      const int T = __ffs(qmask) - 1;
      qmask &= qmask - 1;
      const float dval = dist[(size_t)n * 1024 + T * 64 + lane];
      unsigned long long cm = __ballot(dval <= w);
      while (cm) {
        const int l2 = __ffsll(cm) - 1;
        cm &= cm - 1;
        const int kk = T * 64 + l2;
        const float4 ev = *(const float4*)(emb + ((size_t)kk << 8) + (lane << 2));
        double p = (double)xv.x * ev.x + (double)xv.y * ev.y
                 + (double)xv.z * ev.z + (double)xv.w * ev.w;
#pragma unroll
        for (int mm = 1; mm < 64; mm <<= 1) p += __shfl_xor(p, mm, 64);
        const float dotf = (float)p;
        const float D = __fsub_rn(__fadd_rn(rn, embnorm[kk]), __fmul_rn(2.0f, dotf));
        const unsigned long long c = ((unsigned long long)enc_f(D) << 32) | (unsigned)kk;
        best = c < best ? c : best;
      }
    }
    const int bestk = (int)(best & 0xffffffffu);
    if (lane == 0) {
      bk_s[srow] = bestk;
      out[IDX_OFF + n] = (float)bestk;
      atomicAdd(&counts[bestk], 1.0f);
    }
  }
  __syncthreads();
  {
    const int d = t;
    float zq[16];
    float lsum = 0.f;
#pragma unroll
    for (int r2 = 0; r2 < 16; ++r2) {
      const float e = emb[((size_t)bk_s[r2] << 8) + d];
      const float z = xl[r2][d];
      const float df = __fsub_rn(e, z);
      zq[r2] = __fadd_rn(z, df);          // z + (z_q - z)
      lsum = fmaf(df, df, lsum);
    }
    float* op = out + ZQ_OFF + ((size_t)b << 18) + ((size_t)d << 10) + sb;
#pragma unroll
    for (int q = 0; q < 4; ++q)
      *(float4*)(op + (q << 2)) =
          make_float4(zq[q * 4], zq[q * 4 + 1], zq[q * 4 + 2], zq[q * 4 + 3]);
#pragma unroll
    for (int m = 32; m > 0; m >>= 1) lsum += __shfl_xor(lsum, m, 64);
    if (lane == 0) wredf[wv] = lsum;
  }
  __syncthreads();   // drains all waves' vmem (incl. count atomics) before barrier
  if (t == 0) {
    atomicAdd(lossacc, wredf[0] + wredf[1] + wredf[2] + wredf[3]);
    asm volatile("s_waitcnt vmcnt(0)" ::: "memory");  // loss add complete
    lastflag = (atomicAdd(ctr, 1u) == 2047u) ? 1u : 0u;
  }
  __syncthreads();
  if (!lastflag) return;
  // final: perplexity + loss (device-scope atomic reads are coherent)
  float ssum = 0.f;
#pragma unroll
  for (int u = 0; u < 4; ++u) {
    const float cv = atomicAdd(&counts[t * 4 + u], 0.0f);
    const float p = cv * (1.0f / 32768.0f);
    ssum += p * logf(p + 1e-10f);
  }
#pragma unroll
  for (int m = 32; m > 0; m >>= 1) ssum += __shfl_xor(ssum, m, 64);
  __shared__ float wred2[4];
  if ((t & 63) == 0) wred2[t >> 6] = ssum;
  __syncthreads();
  if (t == 0) {
    const float tot = wred2[0] + wred2[1] + wred2[2] + wred2[3];
    out[PERP_OFF] = expf(-tot);
    const float mql = atomicAdd(lossacc, 0.0f) * (1.0f / 8388608.0f);
    out[LOSS_OFF] = __fadd_rn(mql, __fmul_rn(0.25f, mql));  // q_loss + 0.25*e_loss
  }
}

extern "C" void kernel_launch(void* const* d_in, const int* in_sizes, int n_in,
                              void* d_out, int out_size, void* d_ws, size_t ws_size,
                              hipStream_t stream) {
  const float* z_e = (const float*)d_in[0];
  const float* emb = (const float*)d_in[1];
  float* out = (float*)d_out;
  char* ws = (char*)d_ws;

  unsigned short* ahi = (unsigned short*)(ws + WSB_AHI);
  unsigned short* bhi = (unsigned short*)(ws + WSB_BHI);
  float* rownorm = (float*)(ws + WSB_RN);
  float* embnorm = (float*)(ws + WSB_EN);
  unsigned long long* pkey = (unsigned long long*)(ws + WSB_PKEY);
  float* counts = (float*)(ws + WSB_CNT);
  float* lossacc = (float*)(ws + WSB_LOSS);
  unsigned* ctr = (unsigned*)(ws + WSB_CTR);

  hipLaunchKernelGGL(prep_all_kernel, dim3(645), dim3(256), 0, stream,
                     z_e, emb, ahi, bhi, rownorm, embnorm, counts);
  hipLaunchKernelGGL(dist_kernel, dim3(2048), dim3(256), 0, stream,
                     ahi, bhi, rownorm, embnorm, out + DIST_OFF, pkey);
  hipLaunchKernelGGL(rzq_kernel, dim3(2048), dim3(256), 0, stream,
                     z_e, emb, rownorm, embnorm, out + DIST_OFF, pkey,
                     out, counts, lossacc, ctr);
}

// Round 10
// 119.516 us; speedup vs baseline: 1.4417x; 1.4417x over previous
//
#include <hip/hip_runtime.h>
#include <cfloat>

typedef __attribute__((ext_vector_type(8))) short bf16x8;
typedef __attribute__((ext_vector_type(4))) float f32x4;
typedef __attribute__((ext_vector_type(8))) unsigned short u16x8;

#define NROW 32768
#define ZQ_OFF   0
#define LOSS_OFF 8388608
#define PERP_OFF 8388609
#define IDX_OFF  8388610
#define DIST_OFF 8421378

// ws byte offsets
#define WSB_AHI  0x0
#define WSB_BHI  0x1000000
#define WSB_RN   0x2100000
#define WSB_EN   0x2120000
#define WSB_PKEY 0x2200000
#define WSB_CNT  0x2620000
#define WSB_LOSS 0x2621000

__device__ __forceinline__ float sq_rn(float x) { return __fmul_rn(x, x); }

__device__ __forceinline__ unsigned enc_f(float f) {
  unsigned u = __float_as_uint(f);
  return (u & 0x80000000u) ? ~u : (u | 0x80000000u);
}
__device__ __forceinline__ float dec_f(unsigned e) {
  unsigned u = (e & 0x80000000u) ? (e ^ 0x80000000u) : ~e;
  return __uint_as_float(u);
}

__device__ __forceinline__ unsigned short bf16_rne(float f) {
  unsigned u = __float_as_uint(f);
  unsigned r = u + 0x7fffu + ((u >> 16) & 1u);
  return (unsigned short)(r >> 16);
}

__device__ __forceinline__ void gload16(const void* g, void* l) {
  __builtin_amdgcn_global_load_lds(
      (const __attribute__((address_space(1))) unsigned int*)g,
      (__attribute__((address_space(3))) unsigned int*)l, 16, 0, 0);
}

// numpy pairwise_sum order for 256-length sum of squares (load-bearing).
__device__ float pairwise_norm256(const float* __restrict__ p, int stride) {
  float h[2];
#pragma unroll
  for (int half = 0; half < 2; ++half) {
    const float* q = p + (size_t)half * 128 * stride;
    float r[8];
#pragma unroll
    for (int j = 0; j < 8; ++j) r[j] = sq_rn(q[(size_t)j * stride]);
    for (int d8 = 8; d8 < 128; d8 += 8) {
#pragma unroll
      for (int j = 0; j < 8; ++j)
        r[j] = __fadd_rn(r[j], sq_rn(q[(size_t)(d8 + j) * stride]));
    }
    h[half] = __fadd_rn(__fadd_rn(__fadd_rn(r[0], r[1]), __fadd_rn(r[2], r[3])),
                        __fadd_rn(__fadd_rn(r[4], r[5]), __fadd_rn(r[6], r[7])));
  }
  return __fadd_rn(h[0], h[1]);
}

// One launch for all prep work:
//   blocks 0..511   : z_e -> A bf16 plane (64 rows each) + rownorm (numpy order)
//   blocks 512..639 : emb -> B bf16 plane (pre-swizzled)
//   blocks 640..643 : embnorm
//   block  644      : zero counts+loss
__launch_bounds__(256)
__global__ void prep_all_kernel(const float* __restrict__ z_e,
                                const float* __restrict__ emb,
                                unsigned short* __restrict__ ahi,
                                unsigned short* __restrict__ bhi,
                                float* __restrict__ rownorm,
                                float* __restrict__ embnorm,
                                float* __restrict__ zero_region) {
  __shared__ float xt[64][68];
  __shared__ float hs[64][2];
  const int t = threadIdx.x;
  if (blockIdx.x >= 512) {
    const int bx = blockIdx.x - 512;
    if (bx >= 132) {
      for (int i = t; i < 1026; i += 256) zero_region[i] = 0.f;
      return;
    }
    if (bx >= 128) {
      const int k = ((bx - 128) << 8) + t;
      embnorm[k] = pairwise_norm256(emb + ((size_t)k << 8), 1);
      return;
    }
    const int tg = (bx << 8) + t;   // 32768
    const int k = tg >> 5, cd = tg & 31;
    const float4 v0 = *(const float4*)(emb + ((size_t)k << 8) + cd * 8);
    const float4 v1 = *(const float4*)(emb + ((size_t)k << 8) + cd * 8 + 4);
    const float xs[8] = {v0.x, v0.y, v0.z, v0.w, v1.x, v1.y, v1.z, v1.w};
    u16x8 vh;
#pragma unroll
    for (int u = 0; u < 8; ++u) vh[u] = (short)bf16_rne(xs[u]);
    const size_t pos = (((size_t)(k >> 7)) << 12) + ((size_t)(cd >> 3) << 10)
                     + ((size_t)(k & 127) << 3) + (size_t)((cd & 7) ^ (k & 7));
    *(u16x8*)(bhi + pos * 8) = vh;
    return;
  }
  // ---- A-plane + rownorm: 64 rows per block (2 blocks/CU) ----
  const int bx = blockIdx.x;
  const int ntile = bx >> 1;
  const int shalf = bx & 1;
  const int n0 = bx << 6;                 // first global row of this block
  const int b = n0 >> 10, s0 = n0 & 1023;
  const size_t zb = ((size_t)b << 18) + (size_t)s0;
  const int mys = t & 63;                 // row within block
  const int myhalf = (t >> 6) & 1;        // d-half (valid for t<128)
  float r[8];
#pragma unroll
  for (int j = 0; j < 8; ++j) r[j] = 0.f;   // +0 + x*x bit-exact (squares >= 0)
  for (int dt = 0; dt < 4; ++dt) {
#pragma unroll
    for (int p = 0; p < 4; ++p) {
      const int idx = (p << 8) + t;        // 0..1023
      const int dd = idx >> 4;             // 0..63
      const int sq = (idx & 15) << 2;      // 0..60
      const float4 v = *(const float4*)(z_e + zb + ((size_t)((dt << 6) + dd) << 10) + sq);
      const int sw = ((dd >> 3) & 3) << 3;
      *(float4*)(&xt[dd][sq ^ sw]) = v;
    }
    __syncthreads();
    if (t < 128 && (dt >> 1) == myhalf) {
#pragma unroll
      for (int g = 0; g < 8; ++g) {
        const int col = mys ^ ((g & 3) << 3);
#pragma unroll
        for (int j = 0; j < 8; ++j)
          r[j] = __fadd_rn(r[j], sq_rn(xt[(g << 3) + j][col]));
      }
    }
#pragma unroll
    for (int p = 0; p < 2; ++p) {
      const int idx = (p << 8) + t;        // 0..511
      const int sl = idx >> 3, c = idx & 7;
      const int sw = (c & 3) << 3;
      u16x8 vh;
#pragma unroll
      for (int u = 0; u < 8; ++u)
        vh[u] = (short)bf16_rne(xt[(c << 3) + u][sl ^ sw]);
      const int sg = (shalf << 6) + sl;    // row within 128-row ntile (sg&7==sl&7)
      const size_t pos = ((size_t)ntile << 12) + ((size_t)dt << 10)
                       + (size_t)(sg << 3) + (size_t)(c ^ (sg & 7));
      *(u16x8*)(ahi + pos * 8) = vh;
    }
    __syncthreads();
  }
  if (t < 128) {
    const float h = __fadd_rn(__fadd_rn(__fadd_rn(r[0], r[1]), __fadd_rn(r[2], r[3])),
                              __fadd_rn(__fadd_rn(r[4], r[5]), __fadd_rn(r[6], r[7])));
    hs[mys][myhalf] = h;
  }
  __syncthreads();
  if (t < 64) rownorm[n0 + t] = __fadd_rn(hs[t][0], hs[t][1]);
}

#define LDS_A 0
#define LDS_B 16384

// 128x128 tile, 4 waves of 64x64, single plain-bf16 MFMA per fragment pair
// (proposal eps <= ||x||*||e||*2^-8 ~ 1.2e-3; refine window 3e-3 covers).
// XCD-chunked block mapping for A-tile L2 reuse. (round-8 version, unchanged:
// regular stores — nt stores regressed in round 9.)
__launch_bounds__(256, 4)
__global__ void dist_kernel(const unsigned short* __restrict__ ahi,
                            const unsigned short* __restrict__ bhi,
                            const float* __restrict__ rownorm,
                            const float* __restrict__ embnorm,
                            float* __restrict__ dist,
                            unsigned long long* __restrict__ pkey) {
  __shared__ char lds[32768];
  const int tid = threadIdx.x;
  const int lane = tid & 63;
  const int wv = tid >> 6;
  const int wr = wv >> 1, wc = wv & 1;
  const int bid = blockIdx.x;
  const int xcd = bid & 7;
  const int jj = bid >> 3;
  const int ntile = (xcd << 5) + (jj >> 3);
  const int ktile = jj & 7;

  const unsigned short* gsrc = (wv < 2) ? ahi + ((size_t)ntile << 15)
                                        : bhi + ((size_t)ktile << 15);
  char* ldsBase = lds + ((wv >> 1) << 14);

  f32x4 acc[4][4];
#pragma unroll
  for (int i = 0; i < 4; ++i)
#pragma unroll
    for (int j = 0; j < 4; ++j) acc[i][j] = (f32x4){0.f, 0.f, 0.f, 0.f};

  for (int s = 0; s < 4; ++s) {
    {
      const unsigned short* g = gsrc + ((size_t)s << 13);
#pragma unroll
      for (int q = 0; q < 8; ++q) {
        const int cq = ((wv & 1) << 3) + q;
        gload16(g + ((size_t)(cq * 64 + lane) << 3), ldsBase + cq * 1024);
      }
    }
    __syncthreads();
#pragma unroll
    for (int half = 0; half < 2; ++half) {
      const int kb = half << 2;
      bf16x8 ah[4], bh[4];
#pragma unroll
      for (int i = 0; i < 4; ++i) {
        const int row = (wr << 6) + (i << 4) + (lane & 15);
        const int ch = (kb + (lane >> 4)) ^ (row & 7);
        ah[i] = *(const bf16x8*)(lds + LDS_A + ((row << 3) + ch) * 16);
      }
#pragma unroll
      for (int j = 0; j < 4; ++j) {
        const int row = (wc << 6) + (j << 4) + (lane & 15);
        const int ch = (kb + (lane >> 4)) ^ (row & 7);
        bh[j] = *(const bf16x8*)(lds + LDS_B + ((row << 3) + ch) * 16);
      }
#pragma unroll
      for (int i = 0; i < 4; ++i)
#pragma unroll
        for (int j = 0; j < 4; ++j)
          acc[i][j] = __builtin_amdgcn_mfma_f32_16x16x32_bf16(ah[i], bh[j], acc[i][j], 0, 0, 0);
    }
    __syncthreads();
  }
  const int n0 = (ntile << 7) + (wr << 6);
  const int k0 = (ktile << 7) + (wc << 6);
  const int g = lane >> 4, tl = lane & 15;
  const int tileidx = (ktile << 1) + wc;
  float en[4];
#pragma unroll
  for (int j = 0; j < 4; ++j) en[j] = embnorm[k0 + (j << 4) + tl];
#pragma unroll
  for (int i = 0; i < 4; ++i) {
#pragma unroll
    for (int r = 0; r < 4; ++r) {
      const int n = n0 + (i << 4) + (g << 2) + r;
      const float rn = rownorm[n];
      float* drow = dist + (size_t)n * 1024 + k0 + tl;
      unsigned long long key = ~0ULL;
#pragma unroll
      for (int j = 0; j < 4; ++j) {
        const float dv = __fsub_rn(__fadd_rn(rn, en[j]), __fmul_rn(2.0f, acc[i][j][r]));
        drow[j << 4] = dv;
        const unsigned long long c =
            ((unsigned long long)enc_f(dv) << 32) | (unsigned)(k0 + (j << 4) + tl);
        key = c < key ? c : key;
      }
#pragma unroll
      for (int mm = 1; mm < 16; mm <<= 1) {
        const unsigned long long o = __shfl_xor(key, mm, 64);
        key = o < key ? o : key;
      }
      if (tl == 0) pkey[(size_t)n * 16 + tileidx] = key;
    }
  }
}

// Fused refine + straight-through + loss + histogram + index output.
// (round-8 version, unchanged: no ctr/fused-final — that pattern regressed in
// rounds 7 and 9. 16-wide pkey, 3e-3 window, exact fp64-dot re-eval,
// (value,index) order.)
__launch_bounds__(256)
__global__ void rzq_kernel(const float* __restrict__ z_e,
                           const float* __restrict__ emb,
                           const float* __restrict__ rownorm,
                           const float* __restrict__ embnorm,
                           const float* __restrict__ dist,
                           const unsigned long long* __restrict__ pkey,
                           float* __restrict__ out,
                           float* __restrict__ counts,
                           float* __restrict__ lossacc) {
  __shared__ float xl[16][260];
  __shared__ int bk_s[16];
  __shared__ float wredf[4];
  const int t = threadIdx.x;
  const int s0 = blockIdx.x << 4;
  const int b = s0 >> 10, sb = s0 & 1023;
  {
    const int d = t >> 2;
    const int s4 = (t & 3) << 2;
#pragma unroll
    for (int p = 0; p < 4; ++p) {
      const int dd = d + p * 64;
      const float4 v = *(const float4*)(z_e + ((size_t)b << 18) + ((size_t)dd << 10) + sb + s4);
      xl[s4 + 0][dd] = v.x; xl[s4 + 1][dd] = v.y;
      xl[s4 + 2][dd] = v.z; xl[s4 + 3][dd] = v.w;
    }
  }
  __syncthreads();
  const int wv = t >> 6, lane = t & 63;
  for (int rr = 0; rr < 4; ++rr) {
    const int srow = (wv << 2) + rr;
    const int n = s0 + srow;
    const unsigned long long mypk = (lane < 16) ? pkey[(size_t)n * 16 + lane] : ~0ULL;
    unsigned long long key = mypk;
#pragma unroll
    for (int mm = 1; mm < 64; mm <<= 1) {
      const unsigned long long o = __shfl_xor(key, mm, 64);
      key = o < key ? o : key;
    }
    const float v1 = dec_f((unsigned)(key >> 32));
    const unsigned ue = (__float_as_uint(v1) >> 23) & 0xffu;
    const float ulp = __uint_as_float((ue - 23) << 23);
    const float w = v1 + 2.0f * ulp + 3e-3f;
    unsigned qmask = (unsigned)(__ballot(dec_f((unsigned)(mypk >> 32)) <= w) & 0xffffULL);
    const float rn = rownorm[n];
    const float4 xv = *(const float4*)(&xl[srow][lane << 2]);
    unsigned long long best = ~0ULL;
    while (qmask) {
      const int T = __ffs(qmask) - 1;
      qmask &= qmask - 1;
      const float dval = dist[(size_t)n * 1024 + T * 64 + lane];
      unsigned long long cm = __ballot(dval <= w);
      while (cm) {
        const int l2 = __ffsll(cm) - 1;
        cm &= cm - 1;
        const int kk = T * 64 + l2;
        const float4 ev = *(const float4*)(emb + ((size_t)kk << 8) + (lane << 2));
        double p = (double)xv.x * ev.x + (double)xv.y * ev.y
                 + (double)xv.z * ev.z + (double)xv.w * ev.w;
#pragma unroll
        for (int mm = 1; mm < 64; mm <<= 1) p += __shfl_xor(p, mm, 64);
        const float dotf = (float)p;
        const float D = __fsub_rn(__fadd_rn(rn, embnorm[kk]), __fmul_rn(2.0f, dotf));
        const unsigned long long c = ((unsigned long long)enc_f(D) << 32) | (unsigned)kk;
        best = c < best ? c : best;
      }
    }
    const int bestk = (int)(best & 0xffffffffu);
    if (lane == 0) {
      bk_s[srow] = bestk;
      out[IDX_OFF + n] = (float)bestk;
      atomicAdd(&counts[bestk], 1.0f);
    }
  }
  __syncthreads();
  const int d = t;
  float zq[16];
  float lsum = 0.f;
#pragma unroll
  for (int r2 = 0; r2 < 16; ++r2) {
    const float e = emb[((size_t)bk_s[r2] << 8) + d];
    const float z = xl[r2][d];
    const float df = __fsub_rn(e, z);
    zq[r2] = __fadd_rn(z, df);            // z + (z_q - z)
    lsum = fmaf(df, df, lsum);
  }
  float* op = out + ZQ_OFF + ((size_t)b << 18) + ((size_t)d << 10) + sb;
#pragma unroll
  for (int q = 0; q < 4; ++q)
    *(float4*)(op + (q << 2)) =
        make_float4(zq[q * 4], zq[q * 4 + 1], zq[q * 4 + 2], zq[q * 4 + 3]);
#pragma unroll
  for (int m = 32; m > 0; m >>= 1) lsum += __shfl_xor(lsum, m, 64);
  if (lane == 0) wredf[wv] = lsum;
  __syncthreads();
  if (t == 0) atomicAdd(lossacc, wredf[0] + wredf[1] + wredf[2] + wredf[3]);
}

__launch_bounds__(256)
__global__ void final_kernel(const float* __restrict__ counts, const float* __restrict__ lossacc,
                             float* __restrict__ out) {
  const int t = threadIdx.x;
  float ssum = 0.f;
#pragma unroll
  for (int u = 0; u < 4; ++u) {
    const float p = counts[t * 4 + u] * (1.0f / 32768.0f);
    ssum += p * logf(p + 1e-10f);
  }
#pragma unroll
  for (int m = 32; m > 0; m >>= 1) ssum += __shfl_xor(ssum, m, 64);
  __shared__ float wred[4];
  if ((t & 63) == 0) wred[t >> 6] = ssum;
  __syncthreads();
  if (t == 0) {
    const float tot = wred[0] + wred[1] + wred[2] + wred[3];
    out[PERP_OFF] = expf(-tot);
    const float mql = lossacc[0] * (1.0f / 8388608.0f);
    out[LOSS_OFF] = __fadd_rn(mql, __fmul_rn(0.25f, mql));
  }
}

extern "C" void kernel_launch(void* const* d_in, const int* in_sizes, int n_in,
                              void* d_out, int out_size, void* d_ws, size_t ws_size,
                              hipStream_t stream) {
  const float* z_e = (const float*)d_in[0];
  const float* emb = (const float*)d_in[1];
  float* out = (float*)d_out;
  char* ws = (char*)d_ws;

  unsigned short* ahi = (unsigned short*)(ws + WSB_AHI);
  unsigned short* bhi = (unsigned short*)(ws + WSB_BHI);
  float* rownorm = (float*)(ws + WSB_RN);
  float* embnorm = (float*)(ws + WSB_EN);
  unsigned long long* pkey = (unsigned long long*)(ws + WSB_PKEY);
  float* counts = (float*)(ws + WSB_CNT);
  float* lossacc = (float*)(ws + WSB_LOSS);

  hipLaunchKernelGGL(prep_all_kernel, dim3(645), dim3(256), 0, stream,
                     z_e, emb, ahi, bhi, rownorm, embnorm, counts);
  hipLaunchKernelGGL(dist_kernel, dim3(2048), dim3(256), 0, stream,
                     ahi, bhi, rownorm, embnorm, out + DIST_OFF, pkey);
  hipLaunchKernelGGL(rzq_kernel, dim3(2048), dim3(256), 0, stream,
                     z_e, emb, rownorm, embnorm, out + DIST_OFF, pkey, out, counts, lossacc);
  hipLaunchKernelGGL(final_kernel, dim3(1), dim3(256), 0, stream, counts, lossacc, out);
}